// Round 6
// baseline (968.610 us; speedup 1.0000x reference)
//
#include <hip/hip_runtime.h>

// WindowAttention fused kernels for MI355X (gfx950).
// R6: break the 1-block/CU structural cap (R5: LDS 160KB -> 2 waves/SIMD,
// VALU 21% / MFMA 5.4% / 70% dead cycles, latency-bound).
//  - qkv GEMM moved to pre-pass kernel wa_qkv; q,k stored in MFMA-FRAGMENT
//    layout ([b][h][band 8][lane 64][8]) so main kernel A/B-frags are single
//    coalesced ld16 globals; v stored transposed [b][h][c][row].
//  - rpe tables compacted by inverting relidx: U_qc[jp][i], V_kc[ip][j]
//    (64 used cols instead of 225) -> one [64][132] buffer (33KB inc. W).
//  - W compact per wave: wave wv only touches r in [15*wv, 15*wv+120) ->
//    [128][136] overlay, 4 MFMA K-steps vs 7+fixup, vs per-wave-shifted
//    Tv table tvtw[h][wv][c][128].
//  - LDS 69632 B -> 2 blocks/CU (4 waves/SIMD); 3 barriers/head (was 4).
//  - Fallback: if ws_size < ~202MB, run the verified R5 single-kernel path.

#define SCALE 0.17677669529663687f   // 32^-0.5

typedef __attribute__((ext_vector_type(8))) __bf16 bf16x8;
typedef __attribute__((ext_vector_type(4))) float  f32x4;

__device__ __forceinline__ float bf2f(ushort u){
  union { unsigned int i; float f; } v; v.i = ((unsigned int)u) << 16; return v.f;
}
__device__ __forceinline__ ushort f2bf(float f){
  union { float f; unsigned int i; } v; v.f = f;
  unsigned int r = v.i + 0x7FFFu + ((v.i >> 16) & 1u);   // RNE
  return (ushort)(r >> 16);
}
__device__ __forceinline__ uint pack2(float a, float b){
  return (uint)f2bf(a) | ((uint)f2bf(b) << 16);
}
__device__ __forceinline__ bf16x8 ld16(const ushort* p){          // 16B-aligned
  int4 v = *(const int4*)p;
  return __builtin_bit_cast(bf16x8, v);
}
__device__ __forceinline__ bf16x8 ld8(const ushort* p){           // 8B-aligned
  int2 lo = *(const int2*)p;
  int2 hi = *(const int2*)(p + 4);
  int4 v = make_int4(lo.x, lo.y, hi.x, hi.y);
  return __builtin_bit_cast(bf16x8, v);
}
__device__ __forceinline__ f32x4 mfma16(bf16x8 a, bf16x8 b, f32x4 c){
  return __builtin_amdgcn_mfma_f32_16x16x32_bf16(a, b, c, 0, 0, 0);
}
__device__ __forceinline__ int relidx(int ip, int jp){
  return ((ip >> 3) - (jp >> 3) + 7) * 15 + ((ip & 7) - (jp & 7) + 7);
}

// ---------------- table prep ----------------
// ws (ushorts): wb[49152] | pwb[16384] | rpeb[240*384] | tvt[30720] | tvtw[131072] | q_f | k_f | v_g
__global__ void wa_prep(const float* __restrict__ qkv_w,
                        const float* __restrict__ rpe,
                        const float* __restrict__ proj_w,
                        ushort* __restrict__ wb, ushort* __restrict__ pwb,
                        ushort* __restrict__ rpeb, ushort* __restrict__ tvt,
                        ushort* __restrict__ tvtw){
  int t = blockIdx.x * 256 + threadIdx.x;        // grid 512*256 = 131072
  if (t < 49152) wb[t] = f2bf(qkv_w[t]);
  if (t < 16384) pwb[t] = f2bf(proj_w[t]);
  if (t < 92160){                 // rpeb [240][384] in [3,H,32] packing
    int r = t / 384, c = t % 384;
    int part = c >> 7, rem = c & 127, h = rem >> 5, cc = rem & 31;
    int srcc = h * 96 + part * 32 + cc;
    float v = (r < 225) ? rpe[r * 384 + srcc] * ((part == 0) ? SCALE : 1.0f) : 0.f;
    rpeb[t] = f2bf(v);
  }
  if (t < 30720){                 // old tvt [h][c 32][r 240] (fallback path)
    int r = t % 240, hc = t / 240;
    int h = hc >> 5, c = hc & 31;
    float v = (r < 225) ? rpe[r * 384 + h * 96 + 64 + c] : 0.f;
    tvt[t] = f2bf(v);
  }
  if (t < 131072){                // tvtw [h][w 8][c 32][k 128] = v_rpe[15w+k][c]
    int k = t & 127, c = (t >> 7) & 31, w = (t >> 12) & 7, h = t >> 15;
    int r = 15 * w + k;
    tvtw[t] = f2bf((r <= 224) ? rpe[r * 384 + h * 96 + 64 + c] : 0.f);
  }
}

// ---------------- qkv pre-pass ----------------
// grid 2048 x 256 (4 waves; wave owns 32-row band). Outputs:
//  q_f/k_f [b][h][band 8][lane 64][8]  (MFMA frag layout; q pre-scaled)
//  v_g     [b][h][c 32][row 128]       (transposed)
__global__ __launch_bounds__(256) void wa_qkv(
    const float* __restrict__ x, const float* __restrict__ qkv_b,
    const ushort* __restrict__ wb,
    ushort* __restrict__ q_f, ushort* __restrict__ k_f, ushort* __restrict__ v_g)
{
  __shared__ __align__(16) ushort xs[128 * 136];
  __shared__ __align__(16) ushort st[4][32 * 40];
  const int tid = threadIdx.x, lane = tid & 63, wv4 = tid >> 6;
  const int m16 = lane & 15, q4 = lane >> 4;
  const int b = blockIdx.x;
  const int row0q = wv4 * 32;
  // stage x -> bf16 LDS (2 threads per row)
  {
    int r = tid >> 1, hf = tid & 1;
    const float* src = x + (size_t)b * 16384 + r * 128 + hf * 64;
    ushort* dst = xs + r * 136 + hf * 64;
#pragma unroll
    for (int it = 0; it < 16; ++it){
      float4 f = *(const float4*)(src + it * 4);
      dst[it*4+0] = f2bf(f.x); dst[it*4+1] = f2bf(f.y);
      dst[it*4+2] = f2bf(f.z); dst[it*4+3] = f2bf(f.w);
    }
  }
  __syncthreads();

  for (int h = 0; h < 4; ++h){
    for (int part = 0; part < 3; ++part){
      f32x4 acc[2][2];
#pragma unroll
      for (int mt = 0; mt < 2; ++mt)
#pragma unroll
        for (int sub = 0; sub < 2; ++sub) acc[mt][sub] = f32x4{0.f,0.f,0.f,0.f};
#pragma unroll
      for (int kk = 0; kk < 4; ++kk){
        bf16x8 a[2];
#pragma unroll
        for (int mt = 0; mt < 2; ++mt)
          a[mt] = ld16(xs + (row0q + mt*16 + m16)*136 + kk*32 + q4*8);
#pragma unroll
        for (int sub = 0; sub < 2; ++sub){
          bf16x8 bf = ld16(wb + (part*128 + h*32 + sub*16 + m16)*128 + kk*32 + q4*8);
#pragma unroll
          for (int mt = 0; mt < 2; ++mt) acc[mt][sub] = mfma16(a[mt], bf, acc[mt][sub]);
        }
      }
      if (part < 2){
        float s = (part == 0) ? SCALE : 1.0f;
#pragma unroll
        for (int sub = 0; sub < 2; ++sub){
          float bias = qkv_b[part*128 + h*32 + sub*16 + m16];
#pragma unroll
          for (int mt = 0; mt < 2; ++mt)
#pragma unroll
            for (int r = 0; r < 4; ++r)
              st[wv4][(mt*16 + q4*4 + r)*40 + sub*16 + m16] =
                  f2bf((acc[mt][sub][r] + bias) * s);
        }
        ushort* dstf = (part == 0) ? q_f : k_f;
#pragma unroll
        for (int bandi = 0; bandi < 2; ++bandi){
          bf16x8 fr = ld16(&st[wv4][(bandi*16 + m16)*40 + q4*8]);
          *(int4*)(dstf + (((size_t)(b*4 + h)*8 + wv4*2 + bandi)*64 + lane)*8) =
              __builtin_bit_cast(int4, fr);
        }
      } else {
#pragma unroll
        for (int sub = 0; sub < 2; ++sub){
          float bias = qkv_b[256 + h*32 + sub*16 + m16];
#pragma unroll
          for (int mt = 0; mt < 2; ++mt){
            int rbq = row0q + mt*16 + q4*4;
            uint lo = pack2(acc[mt][sub][0] + bias, acc[mt][sub][1] + bias);
            uint hi = pack2(acc[mt][sub][2] + bias, acc[mt][sub][3] + bias);
            *(uint2*)(v_g + ((size_t)(b*4 + h)*32 + sub*16 + m16)*128 + rbq) =
                make_uint2(lo, hi);
          }
        }
      }
    }
  }
}

// ---------------- main fused kernel (2 blocks/CU) ----------------
__global__ __launch_bounds__(512) void wa_attn_f(
    const float* __restrict__ mask, const float* __restrict__ proj_b,
    const ushort* __restrict__ rpeb, const ushort* __restrict__ tvtw,
    const ushort* __restrict__ pwb,
    const ushort* __restrict__ q_f, const ushort* __restrict__ k_f,
    const ushort* __restrict__ v_g, float* __restrict__ out)
{
  __shared__ __align__(16) ushort sm[34816];     // 69632 B -> 2 blocks/CU
  ushort* uvq = sm;           // [jp|ip 64][row 132] compact U_qc / V_kc
  ushort* Wb  = sm;           // overlay after barrier C: [128][136] compact W
  ushort* ps  = sm + 17408;   // [128][136] p (softmax)

  const int tid  = threadIdx.x;
  const int lane = tid & 63;
  const int wv   = tid >> 6;                      // 0..7
  const int m16  = lane & 15;
  const int q4   = lane >> 4;
  const int b    = blockIdx.x;
  const int wi   = b & 127;
  const int row0 = wv * 16;
  const int rb   = row0 + q4 * 4;                 // even; rows rb..rb+3
  const int ip0  = rb >> 1;                       // even -> ip0+1 same ipr
  const int ip0r = ip0 >> 3, ip0c = ip0 & 7;
  const float* mrow = mask + (size_t)wi * 16384;

  f32x4 po[8];
#pragma unroll
  for (int nt = 0; nt < 8; ++nt) po[nt] = f32x4{0.f,0.f,0.f,0.f};

#pragma clang loop unroll(disable)
  for (int h = 0; h < 4; ++h){
    const size_t bh = (size_t)b*4 + h;
    bf16x8 afq = ld16(q_f + ((bh*8 + wv)*64 + lane)*8);
    // ---- P2: U_qc[jp][i] = q[i]·k_rpe[relidx(ip(i),jp)]  (own rows, inverse-scatter)
#pragma unroll
    for (int nt = 0; nt < 15; ++nt){
      bf16x8 bf = ld16(rpeb + (nt*16 + m16)*384 + 128 + h*32 + q4*8);
      f32x4 d = mfma16(afq, bf, f32x4{0.f,0.f,0.f,0.f});
      int r = nt*16 + m16;
      int s = nt + m16;
      int rdiv = nt + (s >= 15 ? 1 : 0);          // r/15 for r=16nt+m16
      int rmod = s - (s >= 15 ? 15 : 0);          // r%15
      int jpr = ip0r + 7 - rdiv;
      int jpc = ip0c + 7 - rmod;                  // rows rb,rb+1 ; +1 for rb+2,rb+3
      if (r < 225 && (unsigned)jpr < 8u){
        if ((unsigned)jpc < 8u)
          *(uint*)(uvq + (jpr*8 + jpc)*132 + rb) = pack2(d[0], d[1]);
        if ((unsigned)(jpc + 1) < 8u)
          *(uint*)(uvq + (jpr*8 + jpc + 1)*132 + rb + 2) = pack2(d[2], d[3]);
      }
    }
    // ---- P3: S = mask (C-init); qk MFMA (k frags global); U_qc gather
    f32x4 S[8];
#pragma unroll
    for (int nt = 0; nt < 8; ++nt)
#pragma unroll
      for (int r = 0; r < 4; ++r)
        S[nt][r] = mrow[(rb + r)*128 + nt*16 + m16];
#pragma unroll
    for (int nt = 0; nt < 8; ++nt){
      bf16x8 bk = ld16(k_f + ((bh*8 + nt)*64 + lane)*8);
      S[nt] = mfma16(afq, bk, S[nt]);
    }
#pragma unroll
    for (int nt = 0; nt < 8; ++nt){
      int jp = (nt*16 + m16) >> 1;
      uint u0 = *(const uint*)(uvq + jp*132 + rb);
      uint u1 = *(const uint*)(uvq + jp*132 + rb + 2);
      S[nt][0] += bf2f((ushort)(u0 & 0xFFFFu));
      S[nt][1] += bf2f((ushort)(u0 >> 16));
      S[nt][2] += bf2f((ushort)(u1 & 0xFFFFu));
      S[nt][3] += bf2f((ushort)(u1 >> 16));
    }
    // ---- P4: V_kc[ip][j] = k[j]·q_rpe[relidx(ip,jp(j))]  (own rows, inverse-scatter)
    {
      bf16x8 afk = ld16(k_f + ((bh*8 + wv)*64 + lane)*8);
#pragma unroll
      for (int nt = 0; nt < 15; ++nt){
        bf16x8 bf = ld16(rpeb + (nt*16 + m16)*384 + h*32 + q4*8);
        f32x4 d = mfma16(afk, bf, f32x4{0.f,0.f,0.f,0.f});
        int r = nt*16 + m16;
        int s = nt + m16;
        int rdiv = nt + (s >= 15 ? 1 : 0);
        int rmod = s - (s >= 15 ? 15 : 0);
        int ipr  = rdiv + ip0r - 7;               // jp0 = ip0 (rows rb,rb+1)
        int ipc  = rmod + ip0c - 7;               // +1 for rows rb+2,rb+3
        if (r < 225 && (unsigned)ipr < 8u){
          if ((unsigned)ipc < 8u)
            *(uint*)(uvq + (ipr*8 + ipc)*132 + rb) = pack2(d[0], d[1]);
          if ((unsigned)(ipc + 1) < 8u)
            *(uint*)(uvq + (ipr*8 + ipc + 1)*132 + rb + 2) = pack2(d[2], d[3]);
        }
      }
    }
    __syncthreads();   // (B) V_kc all bands visible

    // ---- P5: V_kc gather (1 value / 2 rows) + softmax -> ps (own rows)
#pragma unroll
    for (int nt = 0; nt < 8; ++nt){
      int j = nt*16 + m16;
      float v0 = bf2f(uvq[ip0*132 + j]);
      float v1 = bf2f(uvq[(ip0 + 1)*132 + j]);
      S[nt][0] += v0; S[nt][1] += v0;
      S[nt][2] += v1; S[nt][3] += v1;
    }
#pragma unroll
    for (int r = 0; r < 4; ++r){
      float mx = S[0][r];
#pragma unroll
      for (int nt = 1; nt < 8; ++nt) mx = fmaxf(mx, S[nt][r]);
      mx = fmaxf(mx, __shfl_xor(mx, 1));
      mx = fmaxf(mx, __shfl_xor(mx, 2));
      mx = fmaxf(mx, __shfl_xor(mx, 4));
      mx = fmaxf(mx, __shfl_xor(mx, 8));
      float e[8]; float sum = 0.f;
#pragma unroll
      for (int nt = 0; nt < 8; ++nt){
        e[nt] = exp2f((S[nt][r] - mx) * 1.44269504089f); sum += e[nt];
      }
      sum += __shfl_xor(sum, 1);
      sum += __shfl_xor(sum, 2);
      sum += __shfl_xor(sum, 4);
      sum += __shfl_xor(sum, 8);
      float inv = __builtin_amdgcn_rcpf(sum);
      int i = rb + r;
#pragma unroll
      for (int nt = 0; nt < 8; ++nt) ps[i*136 + nt*16 + m16] = f2bf(e[nt] * inv);
    }
    __syncthreads();   // (C) all pass-B reads of uvq done; W overlay may start

    // ---- P6: out1 = p @ v  (v frags global)
    f32x4 ao[2];
#pragma unroll
    for (int nt = 0; nt < 2; ++nt) ao[nt] = f32x4{0.f,0.f,0.f,0.f};
#pragma unroll
    for (int kk = 0; kk < 4; ++kk){
      bf16x8 ap = ld16(ps + (row0 + m16)*136 + kk*32 + q4*8);
#pragma unroll
      for (int nt = 0; nt < 2; ++nt){
        bf16x8 bv = ld16(v_g + (bh*32 + nt*16 + m16)*128 + kk*32 + q4*8);
        ao[nt] = mfma16(ap, bv, ao[nt]);
      }
    }
    // ---- P7: compact W (cols = r - 15*wv in [0,120)), zero, scatter, W@Tv
    {
#pragma unroll
      for (int it = 0; it < 4; ++it){             // zero own 16 rows x 128 cols
        int idx = it*64 + lane;
        int row = idx >> 4, c8 = (idx & 15)*8;
        *(uint4*)(Wb + (row0 + row)*136 + c8) = make_uint4(0,0,0,0);
      }
    }
#pragma unroll
    for (int it = 0; it < 16; ++it){              // own 16 rows x 64 jp
      int i = row0 + it, jp = lane;
      uint pp = *(const uint*)(ps + i*136 + jp*2);
      float p2 = bf2f((ushort)(pp & 0xFFFFu)) + bf2f((ushort)(pp >> 16));
      int rc = (7 - (jp >> 3))*15 + (((i >> 1) & 7) - (jp & 7) + 7);
      Wb[i*136 + rc] = f2bf(p2);
    }
    // out2 += W @ Tv : 4 K-steps, no fixup (tvtw window [15wv, 15wv+128))
#pragma unroll
    for (int kk = 0; kk < 4; ++kk){
      bf16x8 aw = ld8(Wb + (row0 + m16)*136 + kk*32 + q4*8);
#pragma unroll
      for (int nt = 0; nt < 2; ++nt){
        bf16x8 bt = ld16(tvtw + ((size_t)((h*8 + wv)*32) + nt*16 + m16)*128 + kk*32 + q4*8);
        ao[nt] = mfma16(aw, bt, ao[nt]);
      }
    }
    // ---- proj partial: stage att_h in Wb cols 0..32 (own band), accumulate po
#pragma unroll
    for (int nt = 0; nt < 2; ++nt)
#pragma unroll
      for (int r = 0; r < 4; ++r)
        Wb[(rb + r)*136 + nt*16 + m16] = f2bf(ao[nt][r]);
    {
      bf16x8 aA = ld8(Wb + (row0 + m16)*136 + q4*8);
#pragma unroll
      for (int nt = 0; nt < 8; ++nt){
        bf16x8 bw = ld16(pwb + (nt*16 + m16)*128 + h*32 + q4*8);
        po[nt] = mfma16(aA, bw, po[nt]);
      }
    }
    __syncthreads();   // (F) W/proj reads done before next head's P2 writes
  } // heads

  float* outb = out + (size_t)b * 16384;
#pragma unroll
  for (int nt = 0; nt < 8; ++nt){
    int o = nt*16 + m16;
    float bias = proj_b[o];
#pragma unroll
    for (int r = 0; r < 4; ++r) outb[(rb+r)*128 + o] = po[nt][r] + bias;
  }
}

// ---------------- fallback: verified R5 single-kernel path ----------------
__global__ __launch_bounds__(512) void wa_attn_r5(
    const float* __restrict__ x, const float* __restrict__ mask,
    const float* __restrict__ qkv_b, const float* __restrict__ proj_b,
    const ushort* __restrict__ wb, const ushort* __restrict__ pwb,
    const ushort* __restrict__ rpeb, const ushort* __restrict__ tvt,
    float* __restrict__ out)
{
  __shared__ __align__(16) ushort sm[80136];
  ushort* xs  = sm;
  ushort* qs  = sm + 17408;
  ushort* ks  = sm + 23040;
  ushort* vts = sm + 28672;
  ushort* uvs = sm + 33024;
  ushort* ps  = sm + 62728;

  const int tid  = threadIdx.x;
  const int lane = tid & 63;
  const int wv   = tid >> 6;
  const int m16  = lane & 15;
  const int q4   = lane >> 4;
  const int b    = blockIdx.x;
  const int wi   = b & 127;
  const int row0 = wv * 16;
  const int rb   = row0 + q4 * 4;
  const int ip0  = rb >> 1;
  const float* mrow = mask + (size_t)wi * 16384;

  {
    int r = tid >> 2, qt = tid & 3;
    const float* src = x + (size_t)b * 16384 + r * 128 + qt * 32;
    ushort* dst = xs + r * 136 + qt * 32;
#pragma unroll
    for (int it = 0; it < 8; ++it){
      float4 f = *(const float4*)(src + it * 4);
      dst[it*4+0] = f2bf(f.x); dst[it*4+1] = f2bf(f.y);
      dst[it*4+2] = f2bf(f.z); dst[it*4+3] = f2bf(f.w);
    }
  }
  __syncthreads();

  f32x4 po[8];
#pragma unroll
  for (int nt = 0; nt < 8; ++nt) po[nt] = f32x4{0.f,0.f,0.f,0.f};

#pragma clang loop unroll(disable)
  for (int h = 0; h < 4; ++h){
    {
      f32x4 aqk[6];
#pragma unroll
      for (int nt = 0; nt < 6; ++nt) aqk[nt] = f32x4{0.f,0.f,0.f,0.f};
#pragma unroll
      for (int kk = 0; kk < 4; ++kk){
        bf16x8 a = ld16(xs + (row0 + m16)*136 + kk*32 + q4*8);
#pragma unroll
        for (int nt = 0; nt < 6; ++nt){
          int obase = (nt >> 1)*128 + h*32 + (nt & 1)*16;
          bf16x8 bf = ld16(wb + (obase + m16)*128 + kk*32 + q4*8);
          aqk[nt] = mfma16(a, bf, aqk[nt]);
        }
      }
#pragma unroll
      for (int nt = 0; nt < 6; ++nt){
        int part = nt >> 1;
        int colb = (nt & 1)*16 + m16;
        float bias = qkv_b[part*128 + h*32 + colb];
        float t0 = aqk[nt][0] + bias, t1 = aqk[nt][1] + bias;
        float t2 = aqk[nt][2] + bias, t3 = aqk[nt][3] + bias;
        if (part == 0){
          qs[(rb+0)*44 + colb] = f2bf(t0 * SCALE);
          qs[(rb+1)*44 + colb] = f2bf(t1 * SCALE);
          qs[(rb+2)*44 + colb] = f2bf(t2 * SCALE);
          qs[(rb+3)*44 + colb] = f2bf(t3 * SCALE);
        } else if (part == 1){
          ks[(rb+0)*44 + colb] = f2bf(t0);
          ks[(rb+1)*44 + colb] = f2bf(t1);
          ks[(rb+2)*44 + colb] = f2bf(t2);
          ks[(rb+3)*44 + colb] = f2bf(t3);
        } else {
          *(uint2*)(vts + colb*136 + rb) = make_uint2(pack2(t0,t1), pack2(t2,t3));
        }
      }
    }
    bf16x8 afq = ld8(qs + (row0 + m16)*44 + q4*8);
#pragma unroll
    for (int nt = 0; nt < 15; ++nt){
      bf16x8 bf = ld16(rpeb + (nt*16 + m16)*384 + 128 + h*32 + q4*8);
      f32x4 d = mfma16(afq, bf, f32x4{0.f,0.f,0.f,0.f});
      int col = nt*16 + m16;
      if (col < 225)
        *(uint2*)(uvs + col*132 + rb) = make_uint2(pack2(d[0],d[1]), pack2(d[2],d[3]));
    }
    __syncthreads();
    {
      f32x4 S[8];
#pragma unroll
      for (int nt = 0; nt < 8; ++nt)
#pragma unroll
        for (int r = 0; r < 4; ++r)
          S[nt][r] = mrow[(rb + r) * 128 + nt * 16 + m16];
#pragma unroll
      for (int nt = 0; nt < 8; ++nt){
        bf16x8 bk = ld8(ks + (nt*16 + m16)*44 + q4*8);
        S[nt] = mfma16(afq, bk, S[nt]);
      }
#pragma unroll
      for (int nt = 0; nt < 8; ++nt){
        int jp = (nt*16 + m16) >> 1;
        uint u0 = *(const uint*)(uvs + relidx(ip0,     jp)*132 + rb);
        uint u1 = *(const uint*)(uvs + relidx(ip0 + 1, jp)*132 + rb + 2);
        S[nt][0] += bf2f((ushort)(u0 & 0xFFFFu));
        S[nt][1] += bf2f((ushort)(u0 >> 16));
        S[nt][2] += bf2f((ushort)(u1 & 0xFFFFu));
        S[nt][3] += bf2f((ushort)(u1 >> 16));
      }
      {
        bf16x8 afk = ld8(ks + (row0 + m16)*44 + q4*8);
#pragma unroll
        for (int nt = 0; nt < 15; ++nt){
          bf16x8 bf = ld16(rpeb + (nt*16 + m16)*384 + h*32 + q4*8);
          f32x4 d = mfma16(afk, bf, f32x4{0.f,0.f,0.f,0.f});
          int col = nt*16 + m16;
          if (col < 225)
            *(uint2*)(uvs + col*132 + rb) = make_uint2(pack2(d[0],d[1]), pack2(d[2],d[3]));
        }
      }
      __syncthreads();
#pragma unroll
      for (int nt = 0; nt < 8; ++nt){
        int j = nt*16 + m16, jp = j >> 1;
        float v0 = bf2f(uvs[relidx(ip0,     jp)*132 + j]);
        float v1 = bf2f(uvs[relidx(ip0 + 1, jp)*132 + j]);
        S[nt][0] += v0; S[nt][1] += v0;
        S[nt][2] += v1; S[nt][3] += v1;
      }
#pragma unroll
      for (int r = 0; r < 4; ++r){
        float mx = S[0][r];
#pragma unroll
        for (int nt = 1; nt < 8; ++nt) mx = fmaxf(mx, S[nt][r]);
        mx = fmaxf(mx, __shfl_xor(mx, 1));
        mx = fmaxf(mx, __shfl_xor(mx, 2));
        mx = fmaxf(mx, __shfl_xor(mx, 4));
        mx = fmaxf(mx, __shfl_xor(mx, 8));
        float e[8]; float sum = 0.f;
#pragma unroll
        for (int nt = 0; nt < 8; ++nt){
          e[nt] = exp2f((S[nt][r] - mx) * 1.44269504089f); sum += e[nt];
        }
        sum += __shfl_xor(sum, 1);
        sum += __shfl_xor(sum, 2);
        sum += __shfl_xor(sum, 4);
        sum += __shfl_xor(sum, 8);
        float inv = __builtin_amdgcn_rcpf(sum);
        int i = rb + r;
#pragma unroll
        for (int nt = 0; nt < 8; ++nt) ps[i*136 + nt*16 + m16] = f2bf(e[nt] * inv);
      }
    }
    __syncthreads();
    f32x4 ao[2];
#pragma unroll
    for (int nt = 0; nt < 2; ++nt) ao[nt] = f32x4{0.f,0.f,0.f,0.f};
#pragma unroll
    for (int kk = 0; kk < 4; ++kk){
      bf16x8 ap = ld16(ps + (row0 + m16)*136 + kk*32 + q4*8);
#pragma unroll
      for (int nt = 0; nt < 2; ++nt){
        bf16x8 bv = ld16(vts + (nt*16 + m16)*136 + kk*32 + q4*8);
        ao[nt] = mfma16(ap, bv, ao[nt]);
      }
    }
    {
      uint4* zb = (uint4*)(uvs + row0*228);
#pragma unroll
      for (int it = 0; it < 8; ++it){
        int idx = it*64 + lane;
        if (idx < 456) zb[idx] = make_uint4(0,0,0,0);
      }
    }
#pragma unroll
    for (int it = 0; it < 16; ++it){
      int i = row0 + it, jp = lane;
      uint pp = *(const uint*)(ps + i*136 + jp*2);
      float p2 = bf2f((ushort)(pp & 0xFFFFu)) + bf2f((ushort)(pp >> 16));
      uvs[i*228 + relidx(i >> 1, jp)] = f2bf(p2);
    }
#pragma unroll
    for (int kk = 0; kk < 7; ++kk){
      bf16x8 aw = ld8(uvs + (row0 + m16)*228 + kk*32 + q4*8);
#pragma unroll
      for (int nt = 0; nt < 2; ++nt){
        bf16x8 bt = ld16(tvt + (h*32 + nt*16 + m16)*240 + kk*32 + q4*8);
        ao[nt] = mfma16(aw, bt, ao[nt]);
      }
    }
#pragma unroll
    for (int nt = 0; nt < 2; ++nt){
      float tvv = bf2f(tvt[(h*32 + nt*16 + m16)*240 + 224]);
#pragma unroll
      for (int r = 0; r < 4; ++r)
        ao[nt][r] += bf2f(uvs[(rb+r)*228 + 224]) * tvv;
    }
#pragma unroll
    for (int nt = 0; nt < 2; ++nt)
#pragma unroll
      for (int r = 0; r < 4; ++r)
        qs[(rb+r)*44 + nt*16 + m16] = f2bf(ao[nt][r]);
    {
      bf16x8 aA = ld8(qs + (row0 + m16)*44 + q4*8);
#pragma unroll
      for (int nt = 0; nt < 8; ++nt){
        bf16x8 bw = ld16(pwb + (nt*16 + m16)*128 + h*32 + q4*8);
        po[nt] = mfma16(aA, bw, po[nt]);
      }
    }
    __syncthreads();
  }
  float* outb = out + (size_t)b * 16384;
#pragma unroll
  for (int nt = 0; nt < 8; ++nt){
    int o = nt*16 + m16;
    float bias = proj_b[o];
#pragma unroll
    for (int r = 0; r < 4; ++r) outb[(rb+r)*128 + o] = po[nt][r] + bias;
  }
}

extern "C" void kernel_launch(void* const* d_in, const int* in_sizes, int n_in,
                              void* d_out, int out_size, void* d_ws, size_t ws_size,
                              hipStream_t stream){
  (void)in_sizes; (void)n_in; (void)out_size;
  const float* x      = (const float*)d_in[0];
  const float* mask   = (const float*)d_in[1];
  const float* qkv_w  = (const float*)d_in[2];
  const float* qkv_b  = (const float*)d_in[3];
  const float* rpe    = (const float*)d_in[4];
  const float* proj_w = (const float*)d_in[5];
  const float* proj_b = (const float*)d_in[6];

  ushort* wb   = (ushort*)d_ws;                  // 49152
  ushort* pwb  = wb   + 49152;                   // 16384
  ushort* rpeb = pwb  + 16384;                   // 92160
  ushort* tvt  = rpeb + 92160;                   // 30720
  ushort* tvtw = tvt  + 30720;                   // 131072
  ushort* q_f  = tvtw + 131072;                  // 33554432
  ushort* k_f  = q_f  + 33554432;                // 33554432
  ushort* v_g  = k_f  + 33554432;                // 33554432
  const size_t need = (size_t)(49152 + 16384 + 92160 + 30720 + 131072
                               + 3u * 33554432u) * 2u;   // ~202 MB

  wa_prep<<<512, 256, 0, stream>>>(qkv_w, rpe, proj_w, wb, pwb, rpeb, tvt, tvtw);
  if (ws_size >= need){
    wa_qkv<<<2048, 256, 0, stream>>>(x, qkv_b, wb, q_f, k_f, v_g);
    wa_attn_f<<<2048, 512, 0, stream>>>(mask, proj_b, rpeb, tvtw, pwb,
                                        q_f, k_f, v_g, (float*)d_out);
  } else {
    wa_attn_r5<<<2048, 512, 0, stream>>>(x, mask, qkv_b, proj_b, wb, pwb,
                                         rpeb, tvt, (float*)d_out);
  }
}